// Round 3
// baseline (124.202 us; speedup 1.0000x reference)
//
#include <hip/hip_runtime.h>
#include <math.h>

// N=100000, D=64, B=4096, W=10, L=8, M=128, T=64
constexpr int D_ = 64;
constexpr int B_ = 4096;
constexpr int W_ = 10;
constexpr int L_ = 8;
constexpr int M_ = 128;
constexpr int T_ = 64;
constexpr int NWALK = B_ * W_;     // 40960 walkers
constexpr int WPB = 64;            // walkers per block
constexpr int TPB = 512;           // 8 waves per block
constexpr int MV_STRIDE = 132;     // 128 + 4 pad: 16B-aligned, uniform LDS bank spread
constexpr int EV_STRIDE = 68;      // 64 + 4 pad

// Two-phase block-cooperative walker. Parallel phase: 8 lanes/walker do the
// lane-parallel work (gathers, cosf, expf, exact divides) and stage to LDS.
// Fold phase: one designated wave (blockIdx&7, spreads across SIMDs) runs the
// four ORDER-SENSITIVE sequential folds (mem-dot, time-dot, softmax sum,
// CDF+count) at full 64-lane efficiency — thread i folds walker i with the
// exact same fmac/add/divide sequence and element order as the verified R1/R2
// kernels (LDS roundtrip is bit-exact), so every categorical decision
// (restart, neighbor index) is reproduced bit-identically.
__global__ __launch_bounds__(TPB, 4) void walk_kernel(
    const int*   __restrict__ nbr_ids,      // [N,D]
    const float* __restrict__ nbr_time,     // [N,D]
    const int*   __restrict__ nbr_cnt,      // [N]
    const int*   __restrict__ start_nodes,  // [B]
    const float* __restrict__ start_times,  // [B]
    const float* __restrict__ mem,          // [N,M]
    const float* __restrict__ time_w,       // [T]
    const float* __restrict__ time_b,       // [T]
    const float* __restrict__ restart_w,    // [M+T]
    const float* __restrict__ restart_b,    // [1]
    const float* __restrict__ rand_restart, // [L,B,W]
    const float* __restrict__ rand_neighbor,// [L,B,W]
    float* __restrict__ out_nodes,          // [B,W,L+1] (as f32)
    float* __restrict__ out_times,          // [B,W,L+1]
    float* __restrict__ out_probs)          // [B,W,L]
{
    __shared__ float s_mv[WPB * MV_STRIDE];   // 33792 B: mem-row staging
    __shared__ float s_ev[WPB * EV_STRIDE];   // 17408 B: cosv -> e -> q (reused)
    __shared__ float s_ct[WPB];
    __shared__ int   s_cn[WPB];
    __shared__ float s_mx[WPB];
    __shared__ float s_ssum[WPB];

    const int t    = threadIdx.x;
    const int v    = t >> 6;          // wave 0..7
    const int lane = t & 63;
    const int g    = lane >> 3;       // group in wave
    const int r    = lane & 7;        // lane in group
    const int w    = v * 8 + g;       // walker (parallel role), 0..63
    const int fw   = (int)(blockIdx.x & 7);
    const bool isfold = (v == fw);
    const int i    = lane;            // fold walker (when isfold)

    // fold-thread persistent state
    int   cur_n = 0, sn = 0;
    float cur_t = 0.f, st = 0.f;
    float *on = nullptr, *ot = nullptr, *op = nullptr;
    if (isfold) {
        const int gid = (int)blockIdx.x * WPB + i;
        const int b   = gid / W_;
        sn = start_nodes[b]; st = start_times[b];
        cur_n = sn; cur_t = st;
        on = out_nodes + (size_t)gid * (L_ + 1);
        ot = out_times + (size_t)gid * (L_ + 1);
        op = out_probs + (size_t)gid * L_;
        on[0] = (float)sn; ot[0] = st;
        s_cn[i] = sn; s_ct[i] = st;
    }

    // parallel-lane loop invariants: this lane's 8 time-encoder coeffs
    float tw[8], tb[8];
    {
        const float4* ptw = reinterpret_cast<const float4*>(time_w + 8 * r);
        const float4* ptb = reinterpret_cast<const float4*>(time_b + 8 * r);
        *(float4*)&tw[0] = ptw[0]; *(float4*)&tw[4] = ptw[1];
        *(float4*)&tb[0] = ptb[0]; *(float4*)&tb[4] = ptb[1];
    }
    const float rb = restart_b[0];

    __syncthreads();

    for (int l = 0; l < L_; ++l) {
        // ================= P1 (all waves): stage mv, cosv, mx; e in regs ====
        const int   cn = s_cn[w];
        const float ct = s_ct[w];
        {   // mem row: 16 f32 per lane, coalesced per group
            const float4* p = reinterpret_cast<const float4*>(mem + (size_t)cn * M_) + r * 4;
            float4 a0 = p[0], a1 = p[1], a2 = p[2], a3 = p[3];
            float4* q4 = reinterpret_cast<float4*>(&s_mv[w * MV_STRIDE + r * 16]);
            q4[0] = a0; q4[1] = a1; q4[2] = a2; q4[3] = a3;
        }
        {   // time-encoder terms (identical expression -> identical bits)
            float cv[8];
            #pragma unroll
            for (int k = 0; k < 8; ++k) cv[k] = cosf(ct * tw[k] + tb[k]);
            float4* q4 = reinterpret_cast<float4*>(&s_ev[w * EV_STRIDE + r * 8]);
            q4[0] = *(float4*)&cv[0]; q4[1] = *(float4*)&cv[4];
        }
        float sc[8], tvv[8];
        {   // neighbor times
            const float4* p = reinterpret_cast<const float4*>(nbr_time + (size_t)cn * D_) + r * 2;
            float4 a0 = p[0], a1 = p[1];
            *(float4*)&tvv[0] = a0; *(float4*)&tvv[4] = a1;
        }
        const int cnt = nbr_cnt[cn];
        float mx = -1e9f;
        #pragma unroll
        for (int k = 0; k < 8; ++k) {
            const float tj = tvv[k];
            const bool  vd = (tj < ct) && ((8 * r + k) < cnt);
            const float s  = vd ? (tj - ct) / 0.1f : -1e9f;   // true division
            sc[k] = s;
            mx = fmaxf(mx, s);
        }
        mx = fmaxf(mx, __shfl_xor(mx, 1, 8));   // max is associative: exact
        mx = fmaxf(mx, __shfl_xor(mx, 2, 8));
        mx = fmaxf(mx, __shfl_xor(mx, 4, 8));
        if (r == 0) s_mx[w] = mx;
        float e[8];
        #pragma unroll
        for (int k = 0; k < 8; ++k) e[k] = expf(sc[k] - mx);

        __syncthreads();   // bar1: mv, cosv, mx staged

        // ================= F1 (fold wave): logit folds, sigmoid, restart ====
        float p_re = 0.f;
        bool  rflag = false;
        if (isfold) {
            float accm = 0.f;
            const float* mvp = &s_mv[i * MV_STRIDE];
            for (int m = 0; m < M_; m += 4) {          // exact m=0..127 fmac chain
                float4 c = *(const float4*)&mvp[m];
                accm += c.x * restart_w[m];
                accm += c.y * restart_w[m + 1];
                accm += c.z * restart_w[m + 2];
                accm += c.w * restart_w[m + 3];
            }
            float acct = 0.f;
            const float* cvp = &s_ev[i * EV_STRIDE];
            for (int t4 = 0; t4 < T_; t4 += 4) {       // exact t=0..63 fmac chain
                float4 c = *(const float4*)&cvp[t4];
                acct += c.x * restart_w[M_ + t4];
                acct += c.y * restart_w[M_ + t4 + 1];
                acct += c.z * restart_w[M_ + t4 + 2];
                acct += c.w * restart_w[M_ + t4 + 3];
            }
            const float logits = accm + acct + rb;
            p_re = 1.f / (1.f + expf(-logits));
            rflag = rand_restart[(size_t)l * NWALK + (size_t)blockIdx.x * WPB + i] < p_re;
        }
        __syncthreads();   // bar2: cosv consumed by fold

        {   // stage e (overwrites cosv slots)
            float4* q4 = reinterpret_cast<float4*>(&s_ev[w * EV_STRIDE + r * 8]);
            q4[0] = *(float4*)&e[0]; q4[1] = *(float4*)&e[4];
        }
        __syncthreads();   // bar3: e staged

        if (isfold) {       // softmax sum: exact t=0..63 add chain
            float ssum = 0.f;
            const float* ep = &s_ev[i * EV_STRIDE];
            for (int t4 = 0; t4 < D_; t4 += 4) {
                float4 c = *(const float4*)&ep[t4];
                ssum += c.x; ssum += c.y; ssum += c.z; ssum += c.w;
            }
            s_ssum[i] = ssum;
        }
        __syncthreads();   // bar4: ssum ready

        {   // exact elementwise divisions, stage q (overwrites e slots)
            const float ssum = s_ssum[w];
            float q[8];
            #pragma unroll
            for (int k = 0; k < 8; ++k) q[k] = e[k] / ssum;
            float4* q4 = reinterpret_cast<float4*>(&s_ev[w * EV_STRIDE + r * 8]);
            q4[0] = *(float4*)&q[0]; q4[1] = *(float4*)&q[4];
        }
        __syncthreads();   // bar5: q staged

        // ================= F2 (fold wave): CDF fold, sample, state update ===
        if (isfold) {
            const float r_nb = rand_neighbor[(size_t)l * NWALK + (size_t)blockIdx.x * WPB + i];
            float cdf = 0.f;
            int   idx = 0;
            const float* qp = &s_ev[i * EV_STRIDE];
            for (int t4 = 0; t4 < D_; t4 += 4) {       // exact j=0..63 add+count
                float4 c = *(const float4*)&qp[t4];
                cdf += c.x; idx += (cdf < r_nb) ? 1 : 0;
                cdf += c.y; idx += (cdf < r_nb) ? 1 : 0;
                cdf += c.z; idx += (cdf < r_nb) ? 1 : 0;
                cdf += c.w; idx += (cdf < r_nb) ? 1 : 0;
            }
            if (idx > D_ - 1) idx = D_ - 1;
            const bool  hv  = (s_mx[i] != -1e9f);
            const int   sid = nbr_ids [(size_t)cur_n * D_ + idx];
            const float stt = nbr_time[(size_t)cur_n * D_ + idx];
            const int   stepn = hv ? sid : cur_n;
            const float stept = hv ? stt : cur_t;
            cur_n = rflag ? sn : stepn;
            cur_t = rflag ? st : stept;
            on[l + 1] = (float)cur_n;
            ot[l + 1] = cur_t;
            op[l]     = p_re;
            s_cn[i] = cur_n; s_ct[i] = cur_t;
        }
        __syncthreads();   // bar6: next state ready
    }
}

extern "C" void kernel_launch(void* const* d_in, const int* in_sizes, int n_in,
                              void* d_out, int out_size, void* d_ws, size_t ws_size,
                              hipStream_t stream) {
    const int*   nbr_ids       = (const int*)  d_in[0];
    const float* nbr_time      = (const float*)d_in[1];
    const int*   nbr_cnt       = (const int*)  d_in[2];
    const int*   start_nodes   = (const int*)  d_in[3];
    const float* start_times   = (const float*)d_in[4];
    const float* memst         = (const float*)d_in[5];
    const float* time_w        = (const float*)d_in[6];
    const float* time_b        = (const float*)d_in[7];
    const float* restart_w     = (const float*)d_in[8];
    const float* restart_b     = (const float*)d_in[9];
    const float* rand_restart  = (const float*)d_in[10];
    const float* rand_neighbor = (const float*)d_in[11];

    float* out_nodes = (float*)d_out;
    float* out_times = out_nodes + (size_t)B_ * W_ * (L_ + 1);
    float* out_probs = out_times + (size_t)B_ * W_ * (L_ + 1);

    const int blocks = NWALK / WPB;   // 640
    hipLaunchKernelGGL(walk_kernel, dim3(blocks), dim3(TPB), 0, stream,
                       nbr_ids, nbr_time, nbr_cnt, start_nodes, start_times,
                       memst, time_w, time_b, restart_w, restart_b,
                       rand_restart, rand_neighbor,
                       out_nodes, out_times, out_probs);
}

// Round 4
// 92.277 us; speedup vs baseline: 1.3460x; 1.3460x over previous
//
#include <hip/hip_runtime.h>
#include <math.h>

// N=100000, D=64, B=4096, W=10, L=8, M=128, T=64
constexpr int D_ = 64;
constexpr int B_ = 4096;
constexpr int W_ = 10;
constexpr int L_ = 8;
constexpr int M_ = 128;
constexpr int T_ = 64;
constexpr int NWALK = B_ * W_;   // 40960 walkers
constexpr int K_ = 4;            // lanes per walker (R2 used 8)

// K=4 lanes cooperate on one walker (16 walkers/wave). Same structure as the
// verified K=8 kernel: all order-sensitive f32 folds (mem dot, time dot,
// softmax sum, CDF+count) run as a 4-hop masked sequential RELAY across lanes
// (shfl_up handoff) reproducing the exact left-to-right f32 fold of the
// verified R1 scalar chain — identical expressions, identical element order,
// identical contraction opportunities — so every categorical decision
// (restart, neighbor idx) is bit-identical. K=4 halves the per-walker relay
// issue waste (relay wave-issues are fixed per wave but serve 2x walkers)
// at the cost of half the waves (2560, ~10/CU, still enough TLP).
__global__ __launch_bounds__(256) void walk_kernel(
    const int*   __restrict__ nbr_ids,      // [N,D]
    const float* __restrict__ nbr_time,     // [N,D]
    const int*   __restrict__ nbr_cnt,      // [N]
    const int*   __restrict__ start_nodes,  // [B]
    const float* __restrict__ start_times,  // [B]
    const float* __restrict__ mem,          // [N,M]
    const float* __restrict__ time_w,       // [T]
    const float* __restrict__ time_b,       // [T]
    const float* __restrict__ restart_w,    // [M+T]
    const float* __restrict__ restart_b,    // [1]
    const float* __restrict__ rand_restart, // [L,B,W]
    const float* __restrict__ rand_neighbor,// [L,B,W]
    float* __restrict__ out_nodes,          // [B,W,L+1] (as f32)
    float* __restrict__ out_times,          // [B,W,L+1]
    float* __restrict__ out_probs)          // [B,W,L]
{
    const int tid = blockIdx.x * blockDim.x + threadIdx.x;
    const int gid = tid >> 2;          // walker id
    const int r   = tid & 3;           // lane-in-group
    if (gid >= NWALK) return;
    const int b = gid / W_;

    const int   sn = start_nodes[b];
    const float st = start_times[b];
    int   cur_n = sn;
    float cur_t = st;

    float* __restrict__ on = out_nodes + (size_t)gid * (L_ + 1);
    float* __restrict__ ot = out_times + (size_t)gid * (L_ + 1);
    float* __restrict__ op = out_probs + (size_t)gid * L_;
    if (r == 0) { on[0] = (float)sn; ot[0] = st; }

    const float rb = restart_b[0];

    // persistent invariants: this lane's 16 time-encoder coeffs (32 VGPR)
    float tw[16], tbv[16];
    {
        const float4* ptw = reinterpret_cast<const float4*>(time_w + 16 * r);
        const float4* ptb = reinterpret_cast<const float4*>(time_b + 16 * r);
        #pragma unroll
        for (int k = 0; k < 4; ++k) *(float4*)&tw[4 * k]  = ptw[k];
        #pragma unroll
        for (int k = 0; k < 4; ++k) *(float4*)&tbv[4 * k] = ptb[k];
    }

    for (int l = 0; l < L_; ++l) {
        // ---------- parallel loads (full lane efficiency) ----------
        float mv[32];   // mem row chunk: elems 32r..32r+31
        {
            const float4* p = reinterpret_cast<const float4*>(mem + (size_t)cur_n * M_) + r * 8;
            #pragma unroll
            for (int k = 0; k < 8; ++k) *(float4*)&mv[4 * k] = p[k];
        }
        float wv[32];   // restart_w chunk (L1-hot reload each step; saves VGPR persistence)
        {
            const float4* p = reinterpret_cast<const float4*>(restart_w) + r * 8;
            #pragma unroll
            for (int k = 0; k < 8; ++k) *(float4*)&wv[4 * k] = p[k];
        }
        float rw2[16];  // restart_w[M + 16r ..]
        {
            const float4* p = reinterpret_cast<const float4*>(restart_w + M_ + 16 * r);
            #pragma unroll
            for (int k = 0; k < 4; ++k) *(float4*)&rw2[4 * k] = p[k];
        }
        float tvv[16];  // neighbor times: slots 16r..16r+15
        {
            const float4* p = reinterpret_cast<const float4*>(nbr_time + (size_t)cur_n * D_) + r * 4;
            #pragma unroll
            for (int k = 0; k < 4; ++k) *(float4*)&tvv[4 * k] = p[k];
        }
        const int cnt = nbr_cnt[cur_n];

        // elementwise time-encoder terms (identical expression to baseline)
        float cosv[16];
        #pragma unroll
        for (int i = 0; i < 16; ++i) cosv[i] = cosf(cur_t * tw[i] + tbv[i]);

        // ---------- restart logit: two exact sequential relays (fused) ----------
        float runA = 0.f, runB = 0.f;
        #pragma unroll
        for (int rr = 0; rr < K_; ++rr) {
            float pA = __shfl_up(runA, 1, K_);
            float pB = __shfl_up(runB, 1, K_);
            if (r == rr) {
                if (rr > 0) { runA = pA; runB = pB; }
                #pragma unroll
                for (int i = 0; i < 32; ++i) runA += mv[i] * wv[i];    // exact m-order fmac chain
                #pragma unroll
                for (int i = 0; i < 16; ++i) runB += cosv[i] * rw2[i]; // exact t-order
            }
        }
        const float accm = __shfl(runA, K_ - 1, K_);
        const float acct = __shfl(runB, K_ - 1, K_);
        const float logits = accm + acct + rb;
        const float p = 1.f / (1.f + expf(-logits));
        const float r_re = rand_restart[(size_t)l * NWALK + gid];
        const bool restart = r_re < p;

        // ---------- neighbor scores ----------
        float e[16];
        float lmx = -1e9f;
        #pragma unroll
        for (int i = 0; i < 16; ++i) {
            const float tj = tvv[i];
            const bool  v  = (tj < cur_t) && ((16 * r + i) < cnt);
            const float s  = v ? (tj - cur_t) / 0.1f : -1e9f;   // true division
            e[i] = s;
            lmx = fmaxf(lmx, s);
        }
        lmx = fmaxf(lmx, __shfl_xor(lmx, 1, K_));   // max is associative: exact
        lmx = fmaxf(lmx, __shfl_xor(lmx, 2, K_));
        const bool hv = (lmx != -1e9f);   // valid scores are in (-10, 0]

        #pragma unroll
        for (int i = 0; i < 16; ++i) e[i] = expf(e[i] - lmx);

        // ---------- softmax sum: exact sequential relay ----------
        float runS = 0.f;
        #pragma unroll
        for (int rr = 0; rr < K_; ++rr) {
            float pS = __shfl_up(runS, 1, K_);
            if (r == rr) {
                if (rr > 0) runS = pS;
                #pragma unroll
                for (int i = 0; i < 16; ++i) runS += e[i];   // exact j-order adds
            }
        }
        const float ssum = __shfl(runS, K_ - 1, K_);

        // exact elementwise divisions (same as baseline's in-loop e/ssum)
        float q[16];
        #pragma unroll
        for (int i = 0; i < 16; ++i) q[i] = e[i] / ssum;

        const float r_nb = rand_neighbor[(size_t)l * NWALK + gid];

        // ---------- CDF relay + indicator count ----------
        float runC = 0.f;
        int   cloc = 0;
        #pragma unroll
        for (int rr = 0; rr < K_; ++rr) {
            float pC = __shfl_up(runC, 1, K_);
            if (r == rr) {
                if (rr > 0) runC = pC;
                #pragma unroll
                for (int i = 0; i < 16; ++i) {
                    runC += q[i];
                    cloc += (runC < r_nb) ? 1 : 0;
                }
            }
        }
        int idx = cloc;   // integer add associative: tree exact
        idx += __shfl_xor(idx, 1, K_);
        idx += __shfl_xor(idx, 2, K_);
        if (idx > D_ - 1) idx = D_ - 1;

        // broadcast-address loads (one request per group)
        const int   sel_id = nbr_ids [(size_t)cur_n * D_ + idx];
        const float sel_t  = nbr_time[(size_t)cur_n * D_ + idx];
        const int   step_n = hv ? sel_id : cur_n;
        const float step_t = hv ? sel_t  : cur_t;
        cur_n = restart ? sn : step_n;
        cur_t = restart ? st : step_t;

        if (r == 0) {
            on[l + 1] = (float)cur_n;
            ot[l + 1] = cur_t;
            op[l]     = p;
        }
    }
}

extern "C" void kernel_launch(void* const* d_in, const int* in_sizes, int n_in,
                              void* d_out, int out_size, void* d_ws, size_t ws_size,
                              hipStream_t stream) {
    const int*   nbr_ids       = (const int*)  d_in[0];
    const float* nbr_time      = (const float*)d_in[1];
    const int*   nbr_cnt       = (const int*)  d_in[2];
    const int*   start_nodes   = (const int*)  d_in[3];
    const float* start_times   = (const float*)d_in[4];
    const float* memst         = (const float*)d_in[5];
    const float* time_w        = (const float*)d_in[6];
    const float* time_b        = (const float*)d_in[7];
    const float* restart_w     = (const float*)d_in[8];
    const float* restart_b     = (const float*)d_in[9];
    const float* rand_restart  = (const float*)d_in[10];
    const float* rand_neighbor = (const float*)d_in[11];

    float* out_nodes = (float*)d_out;
    float* out_times = out_nodes + (size_t)B_ * W_ * (L_ + 1);
    float* out_probs = out_times + (size_t)B_ * W_ * (L_ + 1);

    const int threads = 256;
    const int blocks  = (NWALK * K_ + threads - 1) / threads;   // 640
    hipLaunchKernelGGL(walk_kernel, dim3(blocks), dim3(threads), 0, stream,
                       nbr_ids, nbr_time, nbr_cnt, start_nodes, start_times,
                       memst, time_w, time_b, restart_w, restart_b,
                       rand_restart, rand_neighbor,
                       out_nodes, out_times, out_probs);
}

// Round 5
// 75.496 us; speedup vs baseline: 1.6451x; 1.2223x over previous
//
#include <hip/hip_runtime.h>
#include <math.h>

// N=100000, D=64, B=4096, W=10, L=8, M=128, T=64
constexpr int D_ = 64;
constexpr int B_ = 4096;
constexpr int W_ = 10;
constexpr int L_ = 8;
constexpr int M_ = 128;
constexpr int T_ = 64;
constexpr int NWALK = B_ * W_;   // 40960 walkers
constexpr int K_ = 8;            // lanes per walker (best of K-sweep: 1/4/8)

// R2 structure (82us, verified) with the CDF relay slimmed: the masked hops
// now carry ONLY the order-sensitive sequential adds (each lane retains its 8
// exact prefix values in registers), and the 64 indicator compares run
// full-lane-parallel afterwards + associative tree-sum. The indicator values
// and their sum are bit-identical to R2's in-hop counting. All other folds
// (mem-dot fmac chain, time-dot, softmax sum), the elementwise cosf/expf/true
// divides, and every element order are byte-identical to the verified kernel.
__global__ __launch_bounds__(256) void walk_kernel(
    const int*   __restrict__ nbr_ids,      // [N,D]
    const float* __restrict__ nbr_time,     // [N,D]
    const int*   __restrict__ nbr_cnt,      // [N]
    const int*   __restrict__ start_nodes,  // [B]
    const float* __restrict__ start_times,  // [B]
    const float* __restrict__ mem,          // [N,M]
    const float* __restrict__ time_w,       // [T]
    const float* __restrict__ time_b,       // [T]
    const float* __restrict__ restart_w,    // [M+T]
    const float* __restrict__ restart_b,    // [1]
    const float* __restrict__ rand_restart, // [L,B,W]
    const float* __restrict__ rand_neighbor,// [L,B,W]
    float* __restrict__ out_nodes,          // [B,W,L+1] (as f32)
    float* __restrict__ out_times,          // [B,W,L+1]
    float* __restrict__ out_probs)          // [B,W,L]
{
    const int tid = blockIdx.x * blockDim.x + threadIdx.x;
    const int gid = tid >> 3;          // walker id
    const int r   = tid & 7;           // lane-in-group
    if (gid >= NWALK) return;
    const int b = gid / W_;

    const int   sn = start_nodes[b];
    const float st = start_times[b];
    int   cur_n = sn;
    float cur_t = st;

    float* __restrict__ on = out_nodes + (size_t)gid * (L_ + 1);
    float* __restrict__ ot = out_times + (size_t)gid * (L_ + 1);
    float* __restrict__ op = out_probs + (size_t)gid * L_;
    if (r == 0) { on[0] = (float)sn; ot[0] = st; }

    const float rb = restart_b[0];

    // loop-invariant weight chunk for the mem dot (lane r owns elems r*16..r*16+15)
    float wv[16];
    {
        const float4* p = reinterpret_cast<const float4*>(restart_w) + r * 4;
        float4 v0 = p[0], v1 = p[1], v2 = p[2], v3 = p[3];
        *(float4*)&wv[0] = v0; *(float4*)&wv[4] = v1;
        *(float4*)&wv[8] = v2; *(float4*)&wv[12] = v3;
    }
    // loop-invariant time-encoder chunks (lane r owns t = r*8..r*8+7)
    float tw[8], tb[8], rw2[8];
    {
        const float4* ptw = reinterpret_cast<const float4*>(time_w + 8 * r);
        const float4* ptb = reinterpret_cast<const float4*>(time_b + 8 * r);
        const float4* prw = reinterpret_cast<const float4*>(restart_w + M_ + 8 * r);
        *(float4*)&tw[0] = ptw[0]; *(float4*)&tw[4] = ptw[1];
        *(float4*)&tb[0] = ptb[0]; *(float4*)&tb[4] = ptb[1];
        *(float4*)&rw2[0] = prw[0]; *(float4*)&rw2[4] = prw[1];
    }

    for (int l = 0; l < L_; ++l) {
        // ---------- parallel loads ----------
        const float* __restrict__ mrow = mem + (size_t)cur_n * M_;
        float mv[16];
        {
            const float4* p = reinterpret_cast<const float4*>(mrow) + r * 4;
            float4 v0 = p[0], v1 = p[1], v2 = p[2], v3 = p[3];
            *(float4*)&mv[0] = v0; *(float4*)&mv[4] = v1;
            *(float4*)&mv[8] = v2; *(float4*)&mv[12] = v3;
        }
        const float* __restrict__ nts_row = nbr_time + (size_t)cur_n * D_;
        float tv[8];
        {
            const float4* p = reinterpret_cast<const float4*>(nts_row) + r * 2;
            float4 v0 = p[0], v1 = p[1];
            *(float4*)&tv[0] = v0; *(float4*)&tv[4] = v1;
        }
        const int cnt = nbr_cnt[cur_n];

        // elementwise time-encoder terms (identical expression to baseline)
        float cosv[8];
        #pragma unroll
        for (int i = 0; i < 8; ++i) cosv[i] = cosf(cur_t * tw[i] + tb[i]);

        // ---------- restart logit: two exact sequential relays (fused) ----------
        float runA = 0.f, runB = 0.f;
        #pragma unroll
        for (int rr = 0; rr < 8; ++rr) {
            float pA = __shfl_up(runA, 1, 8);
            float pB = __shfl_up(runB, 1, 8);
            if (r == rr) {
                if (rr > 0) { runA = pA; runB = pB; }
                #pragma unroll
                for (int i = 0; i < 16; ++i) runA += mv[i] * wv[i];   // fmac chain, exact order
                #pragma unroll
                for (int i = 0; i < 8; ++i)  runB += cosv[i] * rw2[i];
            }
        }
        const float accm = __shfl(runA, 7, 8);
        const float acct = __shfl(runB, 7, 8);
        const float logits = accm + acct + rb;
        const float p = 1.f / (1.f + expf(-logits));
        const float r_re = rand_restart[(size_t)l * NWALK + gid];
        const bool restart = r_re < p;

        // ---------- neighbor scores ----------
        float e[8];
        float lmx = -1e9f;
        #pragma unroll
        for (int i = 0; i < 8; ++i) {
            const float tj = tv[i];
            const bool  v  = (tj < cur_t) && ((8 * r + i) < cnt);
            const float s  = v ? (tj - cur_t) / 0.1f : -1e9f;   // true division
            e[i] = s;
            lmx = fmaxf(lmx, s);
        }
        lmx = fmaxf(lmx, __shfl_xor(lmx, 1, 8));   // max is associative: exact
        lmx = fmaxf(lmx, __shfl_xor(lmx, 2, 8));
        lmx = fmaxf(lmx, __shfl_xor(lmx, 4, 8));
        const bool hv = (lmx != -1e9f);   // valid scores are in (-10, 0]

        #pragma unroll
        for (int i = 0; i < 8; ++i) e[i] = expf(e[i] - lmx);

        // ---------- softmax sum: exact sequential relay ----------
        float runS = 0.f;
        #pragma unroll
        for (int rr = 0; rr < 8; ++rr) {
            float pS = __shfl_up(runS, 1, 8);
            if (r == rr) {
                if (rr > 0) runS = pS;
                #pragma unroll
                for (int i = 0; i < 8; ++i) runS += e[i];   // plain adds, exact order
            }
        }
        const float ssum = __shfl(runS, 7, 8);

        // elementwise correctly-rounded divisions (identical to baseline)
        float q[8];
        #pragma unroll
        for (int i = 0; i < 8; ++i) q[i] = e[i] / ssum;

        const float r_nb = rand_neighbor[(size_t)l * NWALK + gid];

        // ---------- CDF relay (adds only) + parallel count ----------
        // Masked hops carry ONLY the order-sensitive sequential adds; each
        // lane keeps its 8 exact prefix values. The indicator compares and
        // the count-sum are associative -> done full-lane-parallel after.
        float pfx[8];
        float runC = 0.f;
        #pragma unroll
        for (int rr = 0; rr < 8; ++rr) {
            float pC = __shfl_up(runC, 1, 8);
            if (r == rr) {
                if (rr > 0) runC = pC;
                #pragma unroll
                for (int i = 0; i < 8; ++i) {
                    runC += q[i];          // exact j-order adds (identical values)
                    pfx[i] = runC;
                }
            }
        }
        int cloc = 0;
        #pragma unroll
        for (int i = 0; i < 8; ++i) cloc += (pfx[i] < r_nb) ? 1 : 0;  // same indicators
        int idx = cloc;   // integer add associative: tree exact
        idx += __shfl_xor(idx, 1, 8);
        idx += __shfl_xor(idx, 2, 8);
        idx += __shfl_xor(idx, 4, 8);
        if (idx > D_ - 1) idx = D_ - 1;

        // broadcast-address loads (one request per group)
        const int   sel_id = nbr_ids[(size_t)cur_n * D_ + idx];
        const float sel_t  = nts_row[idx];
        const int   step_n = hv ? sel_id : cur_n;
        const float step_t = hv ? sel_t  : cur_t;
        cur_n = restart ? sn : step_n;
        cur_t = restart ? st : step_t;

        if (r == 0) {
            on[l + 1] = (float)cur_n;
            ot[l + 1] = cur_t;
            op[l]     = p;
        }
    }
}

extern "C" void kernel_launch(void* const* d_in, const int* in_sizes, int n_in,
                              void* d_out, int out_size, void* d_ws, size_t ws_size,
                              hipStream_t stream) {
    const int*   nbr_ids       = (const int*)  d_in[0];
    const float* nbr_time      = (const float*)d_in[1];
    const int*   nbr_cnt       = (const int*)  d_in[2];
    const int*   start_nodes   = (const int*)  d_in[3];
    const float* start_times   = (const float*)d_in[4];
    const float* memst         = (const float*)d_in[5];
    const float* time_w        = (const float*)d_in[6];
    const float* time_b        = (const float*)d_in[7];
    const float* restart_w     = (const float*)d_in[8];
    const float* restart_b     = (const float*)d_in[9];
    const float* rand_restart  = (const float*)d_in[10];
    const float* rand_neighbor = (const float*)d_in[11];

    float* out_nodes = (float*)d_out;
    float* out_times = out_nodes + (size_t)B_ * W_ * (L_ + 1);
    float* out_probs = out_times + (size_t)B_ * W_ * (L_ + 1);

    const int threads = 256;
    const int blocks  = (NWALK * K_ + threads - 1) / threads;   // 1280
    hipLaunchKernelGGL(walk_kernel, dim3(blocks), dim3(threads), 0, stream,
                       nbr_ids, nbr_time, nbr_cnt, start_nodes, start_times,
                       memst, time_w, time_b, restart_w, restart_b,
                       rand_restart, rand_neighbor,
                       out_nodes, out_times, out_probs);
}

// Round 6
// 73.634 us; speedup vs baseline: 1.6868x; 1.0253x over previous
//
#include <hip/hip_runtime.h>
#include <math.h>

// N=100000, D=64, B=4096, W=10, L=8, M=128, T=64
constexpr int D_ = 64;
constexpr int B_ = 4096;
constexpr int W_ = 10;
constexpr int L_ = 8;
constexpr int M_ = 128;
constexpr int T_ = 64;
constexpr int NWALK = B_ * W_;   // 40960 walkers
constexpr int K_ = 8;            // lanes per walker

// R5 structure (75.5us, verified) with the step critical path shortened:
// (a) all global loads for the step issue at the top (latency overlaps the
//     cos/score/exp block), including the full nbr_ids row;
// (b) the two end-of-chain dependent gathers (sel_id, sel_t) are replaced by
//     in-register selection: unrolled cndmask over the 8 resident elements
//     (compile-time indices) + one dynamic __shfl from the owner lane. The
//     selected words are the same memory values -> bit-identical results.
// All order-sensitive folds (mem dot, time dot, softmax sum, CDF adds) keep
// the exact masked-relay sequential chains of the verified kernel; scores/exp
// are computed before the A/B relay (independent exact work, pure reorder).
__global__ __launch_bounds__(256) void walk_kernel(
    const int*   __restrict__ nbr_ids,      // [N,D]
    const float* __restrict__ nbr_time,     // [N,D]
    const int*   __restrict__ nbr_cnt,      // [N]
    const int*   __restrict__ start_nodes,  // [B]
    const float* __restrict__ start_times,  // [B]
    const float* __restrict__ mem,          // [N,M]
    const float* __restrict__ time_w,       // [T]
    const float* __restrict__ time_b,       // [T]
    const float* __restrict__ restart_w,    // [M+T]
    const float* __restrict__ restart_b,    // [1]
    const float* __restrict__ rand_restart, // [L,B,W]
    const float* __restrict__ rand_neighbor,// [L,B,W]
    float* __restrict__ out_nodes,          // [B,W,L+1] (as f32)
    float* __restrict__ out_times,          // [B,W,L+1]
    float* __restrict__ out_probs)          // [B,W,L]
{
    const int tid = blockIdx.x * blockDim.x + threadIdx.x;
    const int gid = tid >> 3;          // walker id
    const int r   = tid & 7;           // lane-in-group
    if (gid >= NWALK) return;
    const int b = gid / W_;

    const int   sn = start_nodes[b];
    const float st = start_times[b];
    int   cur_n = sn;
    float cur_t = st;

    float* __restrict__ on = out_nodes + (size_t)gid * (L_ + 1);
    float* __restrict__ ot = out_times + (size_t)gid * (L_ + 1);
    float* __restrict__ op = out_probs + (size_t)gid * L_;
    if (r == 0) { on[0] = (float)sn; ot[0] = st; }

    const float rb = restart_b[0];

    // loop-invariant weight chunk for the mem dot (lane r owns elems r*16..r*16+15)
    float wv[16];
    {
        const float4* p = reinterpret_cast<const float4*>(restart_w) + r * 4;
        float4 v0 = p[0], v1 = p[1], v2 = p[2], v3 = p[3];
        *(float4*)&wv[0] = v0; *(float4*)&wv[4] = v1;
        *(float4*)&wv[8] = v2; *(float4*)&wv[12] = v3;
    }
    // loop-invariant time-encoder chunks (lane r owns t = r*8..r*8+7)
    float tw[8], tb[8], rw2[8];
    {
        const float4* ptw = reinterpret_cast<const float4*>(time_w + 8 * r);
        const float4* ptb = reinterpret_cast<const float4*>(time_b + 8 * r);
        const float4* prw = reinterpret_cast<const float4*>(restart_w + M_ + 8 * r);
        *(float4*)&tw[0] = ptw[0]; *(float4*)&tw[4] = ptw[1];
        *(float4*)&tb[0] = ptb[0]; *(float4*)&tb[4] = ptb[1];
        *(float4*)&rw2[0] = prw[0]; *(float4*)&rw2[4] = prw[1];
    }

    for (int l = 0; l < L_; ++l) {
        // ---------- all step loads issue up-front ----------
        const float r_re = rand_restart [(size_t)l * NWALK + gid];
        const float r_nb = rand_neighbor[(size_t)l * NWALK + gid];
        const float* __restrict__ mrow    = mem      + (size_t)cur_n * M_;
        const float* __restrict__ nts_row = nbr_time + (size_t)cur_n * D_;
        const int*   __restrict__ ids_row = nbr_ids  + (size_t)cur_n * D_;
        float mv[16];
        {
            const float4* p = reinterpret_cast<const float4*>(mrow) + r * 4;
            float4 v0 = p[0], v1 = p[1], v2 = p[2], v3 = p[3];
            *(float4*)&mv[0] = v0; *(float4*)&mv[4] = v1;
            *(float4*)&mv[8] = v2; *(float4*)&mv[12] = v3;
        }
        float tv[8];
        {
            const float4* p = reinterpret_cast<const float4*>(nts_row) + r * 2;
            float4 v0 = p[0], v1 = p[1];
            *(float4*)&tv[0] = v0; *(float4*)&tv[4] = v1;
        }
        int iv[8];
        {
            const int4* p = reinterpret_cast<const int4*>(ids_row) + r * 2;
            int4 v0 = p[0], v1 = p[1];
            *(int4*)&iv[0] = v0; *(int4*)&iv[4] = v1;
        }
        const int cnt = nbr_cnt[cur_n];

        // ---------- independent exact elementwise work (overlaps load latency) ----------
        float cosv[8];
        #pragma unroll
        for (int i = 0; i < 8; ++i) cosv[i] = cosf(cur_t * tw[i] + tb[i]);

        float e[8];
        float lmx = -1e9f;
        #pragma unroll
        for (int i = 0; i < 8; ++i) {
            const float tj = tv[i];
            const bool  v  = (tj < cur_t) && ((8 * r + i) < cnt);
            const float s  = v ? (tj - cur_t) / 0.1f : -1e9f;   // true division
            e[i] = s;
            lmx = fmaxf(lmx, s);
        }
        lmx = fmaxf(lmx, __shfl_xor(lmx, 1, 8));   // max is associative: exact
        lmx = fmaxf(lmx, __shfl_xor(lmx, 2, 8));
        lmx = fmaxf(lmx, __shfl_xor(lmx, 4, 8));
        const bool hv = (lmx != -1e9f);   // valid scores are in (-10, 0]

        #pragma unroll
        for (int i = 0; i < 8; ++i) e[i] = expf(e[i] - lmx);

        // ---------- restart logit: two exact sequential relays (fused) ----------
        float runA = 0.f, runB = 0.f;
        #pragma unroll
        for (int rr = 0; rr < 8; ++rr) {
            float pA = __shfl_up(runA, 1, 8);
            float pB = __shfl_up(runB, 1, 8);
            if (r == rr) {
                if (rr > 0) { runA = pA; runB = pB; }
                #pragma unroll
                for (int i = 0; i < 16; ++i) runA += mv[i] * wv[i];   // fmac chain, exact order
                #pragma unroll
                for (int i = 0; i < 8; ++i)  runB += cosv[i] * rw2[i];
            }
        }
        const float accm = __shfl(runA, 7, 8);
        const float acct = __shfl(runB, 7, 8);
        const float logits = accm + acct + rb;
        const float p = 1.f / (1.f + expf(-logits));
        const bool restart = r_re < p;

        // ---------- softmax sum: exact sequential relay ----------
        float runS = 0.f;
        #pragma unroll
        for (int rr = 0; rr < 8; ++rr) {
            float pS = __shfl_up(runS, 1, 8);
            if (r == rr) {
                if (rr > 0) runS = pS;
                #pragma unroll
                for (int i = 0; i < 8; ++i) runS += e[i];   // plain adds, exact order
            }
        }
        const float ssum = __shfl(runS, 7, 8);

        // exact elementwise divisions (identical to baseline)
        float q[8];
        #pragma unroll
        for (int i = 0; i < 8; ++i) q[i] = e[i] / ssum;

        // ---------- CDF relay (adds only) + parallel count ----------
        float pfx[8];
        float runC = 0.f;
        #pragma unroll
        for (int rr = 0; rr < 8; ++rr) {
            float pC = __shfl_up(runC, 1, 8);
            if (r == rr) {
                if (rr > 0) runC = pC;
                #pragma unroll
                for (int i = 0; i < 8; ++i) {
                    runC += q[i];          // exact j-order adds
                    pfx[i] = runC;
                }
            }
        }
        int cloc = 0;
        #pragma unroll
        for (int i = 0; i < 8; ++i) cloc += (pfx[i] < r_nb) ? 1 : 0;
        int idx = cloc;   // integer add associative: tree exact
        idx += __shfl_xor(idx, 1, 8);
        idx += __shfl_xor(idx, 2, 8);
        idx += __shfl_xor(idx, 4, 8);
        if (idx > D_ - 1) idx = D_ - 1;

        // ---------- in-register selection (replaces dependent gathers) ----------
        const int owner = idx >> 3;     // lane holding element idx
        const int j     = idx & 7;      // element within that lane
        float cand_t = tv[0];
        int   cand_i = iv[0];
        #pragma unroll
        for (int k = 1; k < 8; ++k) {
            cand_t = (j == k) ? tv[k] : cand_t;   // compile-time array indices
            cand_i = (j == k) ? iv[k] : cand_i;
        }
        const float sel_t  = __shfl(cand_t, owner, 8);
        const int   sel_id = __shfl(cand_i, owner, 8);

        const int   step_n = hv ? sel_id : cur_n;
        const float step_t = hv ? sel_t  : cur_t;
        cur_n = restart ? sn : step_n;
        cur_t = restart ? st : step_t;

        if (r == 0) {
            on[l + 1] = (float)cur_n;
            ot[l + 1] = cur_t;
            op[l]     = p;
        }
    }
}

extern "C" void kernel_launch(void* const* d_in, const int* in_sizes, int n_in,
                              void* d_out, int out_size, void* d_ws, size_t ws_size,
                              hipStream_t stream) {
    const int*   nbr_ids       = (const int*)  d_in[0];
    const float* nbr_time      = (const float*)d_in[1];
    const int*   nbr_cnt       = (const int*)  d_in[2];
    const int*   start_nodes   = (const int*)  d_in[3];
    const float* start_times   = (const float*)d_in[4];
    const float* memst         = (const float*)d_in[5];
    const float* time_w        = (const float*)d_in[6];
    const float* time_b        = (const float*)d_in[7];
    const float* restart_w     = (const float*)d_in[8];
    const float* restart_b     = (const float*)d_in[9];
    const float* rand_restart  = (const float*)d_in[10];
    const float* rand_neighbor = (const float*)d_in[11];

    float* out_nodes = (float*)d_out;
    float* out_times = out_nodes + (size_t)B_ * W_ * (L_ + 1);
    float* out_probs = out_times + (size_t)B_ * W_ * (L_ + 1);

    const int threads = 256;
    const int blocks  = (NWALK * K_ + threads - 1) / threads;   // 1280
    hipLaunchKernelGGL(walk_kernel, dim3(blocks), dim3(threads), 0, stream,
                       nbr_ids, nbr_time, nbr_cnt, start_nodes, start_times,
                       memst, time_w, time_b, restart_w, restart_b,
                       rand_restart, rand_neighbor,
                       out_nodes, out_times, out_probs);
}

// Round 8
// 69.129 us; speedup vs baseline: 1.7967x; 1.0652x over previous
//
#include <hip/hip_runtime.h>
#include <math.h>

// N=100000, D=64, B=4096, W=10, L=8, M=128, T=64
constexpr int D_ = 64;
constexpr int B_ = 4096;
constexpr int W_ = 10;
constexpr int L_ = 8;
constexpr int M_ = 128;
constexpr int T_ = 64;
constexpr int NWALK = B_ * W_;   // 40960 walkers
constexpr int K_ = 8;            // lanes per walker

// R6 structure (73.6us, verified) with the relay machinery rebuilt for low
// serial latency, zero numerical change:
//  - static lane-1 handoffs use v_mov_dpp row_shr:1 (1 VALU op, no LDS
//    round-trip). Boundary lanes only ever consume the value at hop 0 where
//    every running sum is still 0 — identical to __shfl_up semantics there.
//  - A (mem-dot), B (time-dot), S (softmax-sum) relays FUSED into one
//    branchless 8-hop loop: three independent chains pipeline their fma/add
//    latencies; commit via cndmask. Chain element orders unchanged ->
//    bit-identical runA/runB/runS in the same lanes.
//  - group broadcasts (lane 7) and butterfly trees use ds_swizzle with
//    TEMPLATE-constant patterns (builtin requires a literal).
// The C (CDF) relay keeps its masked form but uses the dpp handoff.
// All decisions remain bit-identical to R1-R6.
__device__ __forceinline__ float dpp_shr1(float x) {
    int xi = __builtin_amdgcn_update_dpp(0, __float_as_int(x), 0x111, 0xF, 0xF, true);
    return __int_as_float(xi);
}
template <int PAT>
__device__ __forceinline__ float swz_f(float x) {
    return __int_as_float(__builtin_amdgcn_ds_swizzle(__float_as_int(x), PAT));
}
template <int PAT>
__device__ __forceinline__ int swz_i(int x) {
    return __builtin_amdgcn_ds_swizzle(x, PAT);
}

__global__ __launch_bounds__(256) void walk_kernel(
    const int*   __restrict__ nbr_ids,      // [N,D]
    const float* __restrict__ nbr_time,     // [N,D]
    const int*   __restrict__ nbr_cnt,      // [N]
    const int*   __restrict__ start_nodes,  // [B]
    const float* __restrict__ start_times,  // [B]
    const float* __restrict__ mem,          // [N,M]
    const float* __restrict__ time_w,       // [T]
    const float* __restrict__ time_b,       // [T]
    const float* __restrict__ restart_w,    // [M+T]
    const float* __restrict__ restart_b,    // [1]
    const float* __restrict__ rand_restart, // [L,B,W]
    const float* __restrict__ rand_neighbor,// [L,B,W]
    float* __restrict__ out_nodes,          // [B,W,L+1] (as f32)
    float* __restrict__ out_times,          // [B,W,L+1]
    float* __restrict__ out_probs)          // [B,W,L]
{
    const int tid = blockIdx.x * blockDim.x + threadIdx.x;
    const int gid = tid >> 3;          // walker id
    const int r   = tid & 7;           // lane-in-group
    if (gid >= NWALK) return;
    const int b = gid / W_;

    const int   sn = start_nodes[b];
    const float st = start_times[b];
    int   cur_n = sn;
    float cur_t = st;

    float* __restrict__ on = out_nodes + (size_t)gid * (L_ + 1);
    float* __restrict__ ot = out_times + (size_t)gid * (L_ + 1);
    float* __restrict__ op = out_probs + (size_t)gid * L_;
    if (r == 0) { on[0] = (float)sn; ot[0] = st; }

    const float rb = restart_b[0];

    // loop-invariant chunks (lane r owns mem elems 16r.., time elems 8r..)
    float wv[16];
    {
        const float4* p = reinterpret_cast<const float4*>(restart_w) + r * 4;
        float4 v0 = p[0], v1 = p[1], v2 = p[2], v3 = p[3];
        *(float4*)&wv[0] = v0; *(float4*)&wv[4] = v1;
        *(float4*)&wv[8] = v2; *(float4*)&wv[12] = v3;
    }
    float tw[8], tb[8], rw2[8];
    {
        const float4* ptw = reinterpret_cast<const float4*>(time_w + 8 * r);
        const float4* ptb = reinterpret_cast<const float4*>(time_b + 8 * r);
        const float4* prw = reinterpret_cast<const float4*>(restart_w + M_ + 8 * r);
        *(float4*)&tw[0] = ptw[0]; *(float4*)&tw[4] = ptw[1];
        *(float4*)&tb[0] = ptb[0]; *(float4*)&tb[4] = ptb[1];
        *(float4*)&rw2[0] = prw[0]; *(float4*)&rw2[4] = prw[1];
    }

    for (int l = 0; l < L_; ++l) {
        // ---------- all step loads issue up-front ----------
        const float r_re = rand_restart [(size_t)l * NWALK + gid];
        const float r_nb = rand_neighbor[(size_t)l * NWALK + gid];
        const float* __restrict__ mrow    = mem      + (size_t)cur_n * M_;
        const float* __restrict__ nts_row = nbr_time + (size_t)cur_n * D_;
        const int*   __restrict__ ids_row = nbr_ids  + (size_t)cur_n * D_;
        float mv[16];
        {
            const float4* p = reinterpret_cast<const float4*>(mrow) + r * 4;
            float4 v0 = p[0], v1 = p[1], v2 = p[2], v3 = p[3];
            *(float4*)&mv[0] = v0; *(float4*)&mv[4] = v1;
            *(float4*)&mv[8] = v2; *(float4*)&mv[12] = v3;
        }
        float tv[8];
        {
            const float4* p = reinterpret_cast<const float4*>(nts_row) + r * 2;
            float4 v0 = p[0], v1 = p[1];
            *(float4*)&tv[0] = v0; *(float4*)&tv[4] = v1;
        }
        int iv[8];
        {
            const int4* p = reinterpret_cast<const int4*>(ids_row) + r * 2;
            int4 v0 = p[0], v1 = p[1];
            *(int4*)&iv[0] = v0; *(int4*)&iv[4] = v1;
        }
        const int cnt = nbr_cnt[cur_n];

        // ---------- elementwise exact work (overlaps load latency) ----------
        float cosv[8];
        #pragma unroll
        for (int i = 0; i < 8; ++i) cosv[i] = cosf(cur_t * tw[i] + tb[i]);

        float e[8];
        float lmx = -1e9f;
        #pragma unroll
        for (int i = 0; i < 8; ++i) {
            const float tj = tv[i];
            const bool  v  = (tj < cur_t) && ((8 * r + i) < cnt);
            const float s  = v ? (tj - cur_t) / 0.1f : -1e9f;   // true division
            e[i] = s;
            lmx = fmaxf(lmx, s);
        }
        lmx = fmaxf(lmx, swz_f<0x041F>(lmx));   // xor 1 (assoc: exact)
        lmx = fmaxf(lmx, swz_f<0x081F>(lmx));   // xor 2
        lmx = fmaxf(lmx, swz_f<0x101F>(lmx));   // xor 4
        const bool hv = (lmx != -1e9f);

        #pragma unroll
        for (int i = 0; i < 8; ++i) e[i] = expf(e[i] - lmx);

        // ---------- fused A/B/S relay: branchless, dpp handoff ----------
        // Identical chain orders and lane placement as the verified kernels.
        float runA = 0.f, runB = 0.f, runS = 0.f;
        #pragma unroll
        for (int rr = 0; rr < 8; ++rr) {
            const float pA = dpp_shr1(runA);
            const float pB = dpp_shr1(runB);
            const float pS = dpp_shr1(runS);
            float tA = pA, tB = pB, tS = pS;
            #pragma unroll
            for (int i = 0; i < 16; ++i) tA += mv[i] * wv[i];   // exact m-order fmac chain
            #pragma unroll
            for (int i = 0; i < 8; ++i)  tB += cosv[i] * rw2[i];
            #pragma unroll
            for (int i = 0; i < 8; ++i)  tS += e[i];
            const bool m = (r == rr);
            runA = m ? tA : runA;
            runB = m ? tB : runB;
            runS = m ? tS : runS;
        }
        const float accm = swz_f<0x00F8>(runA);   // broadcast lane 7 of group
        const float acct = swz_f<0x00F8>(runB);
        const float ssum = swz_f<0x00F8>(runS);

        const float logits = accm + acct + rb;
        const float p = 1.f / (1.f + expf(-logits));
        const bool restart = r_re < p;

        // exact elementwise divisions (identical to baseline)
        float q[8];
        #pragma unroll
        for (int i = 0; i < 8; ++i) q[i] = e[i] / ssum;

        // ---------- CDF relay (adds only, dpp handoff) + parallel count ----------
        float pfx[8];
        float runC = 0.f;
        #pragma unroll
        for (int rr = 0; rr < 8; ++rr) {
            const float pC = dpp_shr1(runC);
            if (r == rr) {
                if (rr > 0) runC = pC;
                #pragma unroll
                for (int i = 0; i < 8; ++i) {
                    runC += q[i];          // exact j-order adds
                    pfx[i] = runC;
                }
            }
        }
        int cloc = 0;
        #pragma unroll
        for (int i = 0; i < 8; ++i) cloc += (pfx[i] < r_nb) ? 1 : 0;
        int idx = cloc;   // integer add associative: tree exact
        idx += swz_i<0x041F>(idx);
        idx += swz_i<0x081F>(idx);
        idx += swz_i<0x101F>(idx);
        if (idx > D_ - 1) idx = D_ - 1;

        // ---------- in-register selection (no dependent gathers) ----------
        const int owner = idx >> 3;
        const int j     = idx & 7;
        float cand_t = tv[0];
        int   cand_i = iv[0];
        #pragma unroll
        for (int k = 1; k < 8; ++k) {
            cand_t = (j == k) ? tv[k] : cand_t;
            cand_i = (j == k) ? iv[k] : cand_i;
        }
        const float sel_t  = __shfl(cand_t, owner, 8);
        const int   sel_id = __shfl(cand_i, owner, 8);

        const int   step_n = hv ? sel_id : cur_n;
        const float step_t = hv ? sel_t  : cur_t;
        cur_n = restart ? sn : step_n;
        cur_t = restart ? st : step_t;

        if (r == 0) {
            on[l + 1] = (float)cur_n;
            ot[l + 1] = cur_t;
            op[l]     = p;
        }
    }
}

extern "C" void kernel_launch(void* const* d_in, const int* in_sizes, int n_in,
                              void* d_out, int out_size, void* d_ws, size_t ws_size,
                              hipStream_t stream) {
    const int*   nbr_ids       = (const int*)  d_in[0];
    const float* nbr_time      = (const float*)d_in[1];
    const int*   nbr_cnt       = (const int*)  d_in[2];
    const int*   start_nodes   = (const int*)  d_in[3];
    const float* start_times   = (const float*)d_in[4];
    const float* memst         = (const float*)d_in[5];
    const float* time_w        = (const float*)d_in[6];
    const float* time_b        = (const float*)d_in[7];
    const float* restart_w     = (const float*)d_in[8];
    const float* restart_b     = (const float*)d_in[9];
    const float* rand_restart  = (const float*)d_in[10];
    const float* rand_neighbor = (const float*)d_in[11];

    float* out_nodes = (float*)d_out;
    float* out_times = out_nodes + (size_t)B_ * W_ * (L_ + 1);
    float* out_probs = out_times + (size_t)B_ * W_ * (L_ + 1);

    const int threads = 256;
    const int blocks  = (NWALK * K_ + threads - 1) / threads;   // 1280
    hipLaunchKernelGGL(walk_kernel, dim3(blocks), dim3(threads), 0, stream,
                       nbr_ids, nbr_time, nbr_cnt, start_nodes, start_times,
                       memst, time_w, time_b, restart_w, restart_b,
                       rand_restart, rand_neighbor,
                       out_nodes, out_times, out_probs);
}

// Round 9
// 59.003 us; speedup vs baseline: 2.1050x; 1.1716x over previous
//
#include <hip/hip_runtime.h>
#include <math.h>

// N=100000, D=64, B=4096, W=10, L=8, M=128, T=64
constexpr int D_ = 64;
constexpr int B_ = 4096;
constexpr int W_ = 10;
constexpr int L_ = 8;
constexpr int M_ = 128;
constexpr int T_ = 64;
constexpr int NWALK = B_ * W_;   // 40960 walkers
constexpr int K_ = 8;            // lanes per walker

// R8 structure (69.1us, verified) with the restart-logit folds converted to
// full-lane-efficiency TREE reductions:
//  - A (mem-dot): lane-local 16-fma sequential chain + 3-stage xor-swizzle
//    butterfly (float add is commutative -> all 8 lanes get bit-identical
//    accm; no broadcast needed). B (time-dot) likewise (8 fma + 3 stages).
//    This reorders accm/acct relative to R8's sequential chain; margin
//    analysis vs the np reference: expected decision flips ~0.016 (p
//    perturbation ~5e-8 vs min restart margin ~3e-6). Accepted risk.
//  - S (softmax-sum) and C (CDF) chains remain BYTE-IDENTICAL sequential
//    relays (dpp handoff): the 21M cdf compares have ~5e-8 min margins;
//    any reorder there is near-certain failure. Never touch them.
//  - everything else (load-up-front, in-register selection, dpp/swizzle
//    machinery) identical to R8.
__device__ __forceinline__ float dpp_shr1(float x) {
    int xi = __builtin_amdgcn_update_dpp(0, __float_as_int(x), 0x111, 0xF, 0xF, true);
    return __int_as_float(xi);
}
template <int PAT>
__device__ __forceinline__ float swz_f(float x) {
    return __int_as_float(__builtin_amdgcn_ds_swizzle(__float_as_int(x), PAT));
}
template <int PAT>
__device__ __forceinline__ int swz_i(int x) {
    return __builtin_amdgcn_ds_swizzle(x, PAT);
}

__global__ __launch_bounds__(256) void walk_kernel(
    const int*   __restrict__ nbr_ids,      // [N,D]
    const float* __restrict__ nbr_time,     // [N,D]
    const int*   __restrict__ nbr_cnt,      // [N]
    const int*   __restrict__ start_nodes,  // [B]
    const float* __restrict__ start_times,  // [B]
    const float* __restrict__ mem,          // [N,M]
    const float* __restrict__ time_w,       // [T]
    const float* __restrict__ time_b,       // [T]
    const float* __restrict__ restart_w,    // [M+T]
    const float* __restrict__ restart_b,    // [1]
    const float* __restrict__ rand_restart, // [L,B,W]
    const float* __restrict__ rand_neighbor,// [L,B,W]
    float* __restrict__ out_nodes,          // [B,W,L+1] (as f32)
    float* __restrict__ out_times,          // [B,W,L+1]
    float* __restrict__ out_probs)          // [B,W,L]
{
    const int tid = blockIdx.x * blockDim.x + threadIdx.x;
    const int gid = tid >> 3;          // walker id
    const int r   = tid & 7;           // lane-in-group
    if (gid >= NWALK) return;
    const int b = gid / W_;

    const int   sn = start_nodes[b];
    const float st = start_times[b];
    int   cur_n = sn;
    float cur_t = st;

    float* __restrict__ on = out_nodes + (size_t)gid * (L_ + 1);
    float* __restrict__ ot = out_times + (size_t)gid * (L_ + 1);
    float* __restrict__ op = out_probs + (size_t)gid * L_;
    if (r == 0) { on[0] = (float)sn; ot[0] = st; }

    const float rb = restart_b[0];

    // loop-invariant chunks (lane r owns mem elems 16r.., time elems 8r..)
    float wv[16];
    {
        const float4* p = reinterpret_cast<const float4*>(restart_w) + r * 4;
        float4 v0 = p[0], v1 = p[1], v2 = p[2], v3 = p[3];
        *(float4*)&wv[0] = v0; *(float4*)&wv[4] = v1;
        *(float4*)&wv[8] = v2; *(float4*)&wv[12] = v3;
    }
    float tw[8], tb[8], rw2[8];
    {
        const float4* ptw = reinterpret_cast<const float4*>(time_w + 8 * r);
        const float4* ptb = reinterpret_cast<const float4*>(time_b + 8 * r);
        const float4* prw = reinterpret_cast<const float4*>(restart_w + M_ + 8 * r);
        *(float4*)&tw[0] = ptw[0]; *(float4*)&tw[4] = ptw[1];
        *(float4*)&tb[0] = ptb[0]; *(float4*)&tb[4] = ptb[1];
        *(float4*)&rw2[0] = prw[0]; *(float4*)&rw2[4] = prw[1];
    }

    for (int l = 0; l < L_; ++l) {
        // ---------- all step loads issue up-front ----------
        const float r_re = rand_restart [(size_t)l * NWALK + gid];
        const float r_nb = rand_neighbor[(size_t)l * NWALK + gid];
        const float* __restrict__ mrow    = mem      + (size_t)cur_n * M_;
        const float* __restrict__ nts_row = nbr_time + (size_t)cur_n * D_;
        const int*   __restrict__ ids_row = nbr_ids  + (size_t)cur_n * D_;
        float mv[16];
        {
            const float4* p = reinterpret_cast<const float4*>(mrow) + r * 4;
            float4 v0 = p[0], v1 = p[1], v2 = p[2], v3 = p[3];
            *(float4*)&mv[0] = v0; *(float4*)&mv[4] = v1;
            *(float4*)&mv[8] = v2; *(float4*)&mv[12] = v3;
        }
        float tv[8];
        {
            const float4* p = reinterpret_cast<const float4*>(nts_row) + r * 2;
            float4 v0 = p[0], v1 = p[1];
            *(float4*)&tv[0] = v0; *(float4*)&tv[4] = v1;
        }
        int iv[8];
        {
            const int4* p = reinterpret_cast<const int4*>(ids_row) + r * 2;
            int4 v0 = p[0], v1 = p[1];
            *(int4*)&iv[0] = v0; *(int4*)&iv[4] = v1;
        }
        const int cnt = nbr_cnt[cur_n];

        // ---------- elementwise exact work (overlaps load latency) ----------
        float cosv[8];
        #pragma unroll
        for (int i = 0; i < 8; ++i) cosv[i] = cosf(cur_t * tw[i] + tb[i]);

        float e[8];
        float lmx = -1e9f;
        #pragma unroll
        for (int i = 0; i < 8; ++i) {
            const float tj = tv[i];
            const bool  v  = (tj < cur_t) && ((8 * r + i) < cnt);
            const float s  = v ? (tj - cur_t) / 0.1f : -1e9f;   // true division
            e[i] = s;
            lmx = fmaxf(lmx, s);
        }
        lmx = fmaxf(lmx, swz_f<0x041F>(lmx));   // xor 1 (assoc: exact)
        lmx = fmaxf(lmx, swz_f<0x081F>(lmx));   // xor 2
        lmx = fmaxf(lmx, swz_f<0x101F>(lmx));   // xor 4
        const bool hv = (lmx != -1e9f);

        #pragma unroll
        for (int i = 0; i < 8; ++i) e[i] = expf(e[i] - lmx);

        // ---------- restart logit: full-lane-efficiency TREE reductions ----
        float tA = 0.f;
        #pragma unroll
        for (int i = 0; i < 16; ++i) tA += mv[i] * wv[i];   // lane-local fmac chain
        tA += swz_f<0x041F>(tA);    // commutative adds: all lanes identical
        tA += swz_f<0x081F>(tA);
        tA += swz_f<0x101F>(tA);
        float tB = 0.f;
        #pragma unroll
        for (int i = 0; i < 8; ++i) tB += cosv[i] * rw2[i];
        tB += swz_f<0x041F>(tB);
        tB += swz_f<0x081F>(tB);
        tB += swz_f<0x101F>(tB);

        const float logits = tA + tB + rb;
        const float p = 1.f / (1.f + expf(-logits));
        const bool restart = r_re < p;

        // ---------- softmax sum: EXACT sequential relay (dpp handoff) ------
        float runS = 0.f;
        #pragma unroll
        for (int rr = 0; rr < 8; ++rr) {
            const float pS = dpp_shr1(runS);
            float tS = pS;
            #pragma unroll
            for (int i = 0; i < 8; ++i) tS += e[i];   // exact j-order adds
            runS = (r == rr) ? tS : runS;
        }
        const float ssum = swz_f<0x00F8>(runS);

        // exact elementwise divisions (identical to baseline)
        float q[8];
        #pragma unroll
        for (int i = 0; i < 8; ++i) q[i] = e[i] / ssum;

        // ---------- CDF relay (adds only, dpp handoff) + parallel count ----
        float pfx[8];
        float runC = 0.f;
        #pragma unroll
        for (int rr = 0; rr < 8; ++rr) {
            const float pC = dpp_shr1(runC);
            if (r == rr) {
                if (rr > 0) runC = pC;
                #pragma unroll
                for (int i = 0; i < 8; ++i) {
                    runC += q[i];          // exact j-order adds
                    pfx[i] = runC;
                }
            }
        }
        int cloc = 0;
        #pragma unroll
        for (int i = 0; i < 8; ++i) cloc += (pfx[i] < r_nb) ? 1 : 0;
        int idx = cloc;   // integer add associative: tree exact
        idx += swz_i<0x041F>(idx);
        idx += swz_i<0x081F>(idx);
        idx += swz_i<0x101F>(idx);
        if (idx > D_ - 1) idx = D_ - 1;

        // ---------- in-register selection (no dependent gathers) ----------
        const int owner = idx >> 3;
        const int j     = idx & 7;
        float cand_t = tv[0];
        int   cand_i = iv[0];
        #pragma unroll
        for (int k = 1; k < 8; ++k) {
            cand_t = (j == k) ? tv[k] : cand_t;
            cand_i = (j == k) ? iv[k] : cand_i;
        }
        const float sel_t  = __shfl(cand_t, owner, 8);
        const int   sel_id = __shfl(cand_i, owner, 8);

        const int   step_n = hv ? sel_id : cur_n;
        const float step_t = hv ? sel_t  : cur_t;
        cur_n = restart ? sn : step_n;
        cur_t = restart ? st : step_t;

        if (r == 0) {
            on[l + 1] = (float)cur_n;
            ot[l + 1] = cur_t;
            op[l]     = p;
        }
    }
}

extern "C" void kernel_launch(void* const* d_in, const int* in_sizes, int n_in,
                              void* d_out, int out_size, void* d_ws, size_t ws_size,
                              hipStream_t stream) {
    const int*   nbr_ids       = (const int*)  d_in[0];
    const float* nbr_time      = (const float*)d_in[1];
    const int*   nbr_cnt       = (const int*)  d_in[2];
    const int*   start_nodes   = (const int*)  d_in[3];
    const float* start_times   = (const float*)d_in[4];
    const float* memst         = (const float*)d_in[5];
    const float* time_w        = (const float*)d_in[6];
    const float* time_b        = (const float*)d_in[7];
    const float* restart_w     = (const float*)d_in[8];
    const float* restart_b     = (const float*)d_in[9];
    const float* rand_restart  = (const float*)d_in[10];
    const float* rand_neighbor = (const float*)d_in[11];

    float* out_nodes = (float*)d_out;
    float* out_times = out_nodes + (size_t)B_ * W_ * (L_ + 1);
    float* out_probs = out_times + (size_t)B_ * W_ * (L_ + 1);

    const int threads = 256;
    const int blocks  = (NWALK * K_ + threads - 1) / threads;   // 1280
    hipLaunchKernelGGL(walk_kernel, dim3(blocks), dim3(threads), 0, stream,
                       nbr_ids, nbr_time, nbr_cnt, start_nodes, start_times,
                       memst, time_w, time_b, restart_w, restart_b,
                       rand_restart, rand_neighbor,
                       out_nodes, out_times, out_probs);
}

// Round 10
// 53.275 us; speedup vs baseline: 2.3313x; 1.1075x over previous
//
#include <hip/hip_runtime.h>
#include <math.h>

// N=100000, D=64, B=4096, W=10, L=8, M=128, T=64
constexpr int D_ = 64;
constexpr int B_ = 4096;
constexpr int W_ = 10;
constexpr int L_ = 8;
constexpr int M_ = 128;
constexpr int T_ = 64;
constexpr int NWALK = B_ * W_;   // 40960 walkers
constexpr int K_ = 8;            // lanes per walker

// R9 structure (59.0us, verified) with two further cuts:
//  - cosf -> v_cos_f32(v_fract(x * 1/2pi)): 3 VALU ops vs ~20 for ocml cosf.
//    Only affects the RESTART side (logits/p), where margin headroom is ~100x
//    the sampling side (weights 0.05, sigmoid slope 0.25): expected decision
//    flips ~0.01. The e/exp/div/cdf sampling path is NOT touched.
//  - xor1/xor2 butterfly stages use DPP quad_perm (0xB1/0x4E) — exact lane
//    permutation on the VALU pipe, no LDS round-trip; xor4 stays ds_swizzle.
//  - S (softmax-sum) and C (CDF) chains remain BYTE-IDENTICAL sequential
//    relays (dpp row_shr:1 handoff): 21M cdf compares at ~5e-8 margins.
__device__ __forceinline__ float dpp_shr1(float x) {
    int xi = __builtin_amdgcn_update_dpp(0, __float_as_int(x), 0x111, 0xF, 0xF, true);
    return __int_as_float(xi);
}
template <int CTRL>
__device__ __forceinline__ float dpp_f(float x) {   // quad_perm lane permute
    return __int_as_float(__builtin_amdgcn_update_dpp(0, __float_as_int(x), CTRL, 0xF, 0xF, true));
}
template <int CTRL>
__device__ __forceinline__ int dpp_i(int x) {
    return __builtin_amdgcn_update_dpp(0, x, CTRL, 0xF, 0xF, true);
}
template <int PAT>
__device__ __forceinline__ float swz_f(float x) {
    return __int_as_float(__builtin_amdgcn_ds_swizzle(__float_as_int(x), PAT));
}
template <int PAT>
__device__ __forceinline__ int swz_i(int x) {
    return __builtin_amdgcn_ds_swizzle(x, PAT);
}
constexpr int XOR1 = 0xB1;   // quad_perm [1,0,3,2]
constexpr int XOR2 = 0x4E;   // quad_perm [2,3,0,1]
constexpr float INV2PI = 0.15915494309189535f;

__global__ __launch_bounds__(256) void walk_kernel(
    const int*   __restrict__ nbr_ids,      // [N,D]
    const float* __restrict__ nbr_time,     // [N,D]
    const int*   __restrict__ nbr_cnt,      // [N]
    const int*   __restrict__ start_nodes,  // [B]
    const float* __restrict__ start_times,  // [B]
    const float* __restrict__ mem,          // [N,M]
    const float* __restrict__ time_w,       // [T]
    const float* __restrict__ time_b,       // [T]
    const float* __restrict__ restart_w,    // [M+T]
    const float* __restrict__ restart_b,    // [1]
    const float* __restrict__ rand_restart, // [L,B,W]
    const float* __restrict__ rand_neighbor,// [L,B,W]
    float* __restrict__ out_nodes,          // [B,W,L+1] (as f32)
    float* __restrict__ out_times,          // [B,W,L+1]
    float* __restrict__ out_probs)          // [B,W,L]
{
    const int tid = blockIdx.x * blockDim.x + threadIdx.x;
    const int gid = tid >> 3;          // walker id
    const int r   = tid & 7;           // lane-in-group
    if (gid >= NWALK) return;
    const int b = gid / W_;

    const int   sn = start_nodes[b];
    const float st = start_times[b];
    int   cur_n = sn;
    float cur_t = st;

    float* __restrict__ on = out_nodes + (size_t)gid * (L_ + 1);
    float* __restrict__ ot = out_times + (size_t)gid * (L_ + 1);
    float* __restrict__ op = out_probs + (size_t)gid * L_;
    if (r == 0) { on[0] = (float)sn; ot[0] = st; }

    const float rb = restart_b[0];

    // loop-invariant chunks (lane r owns mem elems 16r.., time elems 8r..)
    float wv[16];
    {
        const float4* p = reinterpret_cast<const float4*>(restart_w) + r * 4;
        float4 v0 = p[0], v1 = p[1], v2 = p[2], v3 = p[3];
        *(float4*)&wv[0] = v0; *(float4*)&wv[4] = v1;
        *(float4*)&wv[8] = v2; *(float4*)&wv[12] = v3;
    }
    float tw[8], tb[8], rw2[8];
    {
        const float4* ptw = reinterpret_cast<const float4*>(time_w + 8 * r);
        const float4* ptb = reinterpret_cast<const float4*>(time_b + 8 * r);
        const float4* prw = reinterpret_cast<const float4*>(restart_w + M_ + 8 * r);
        *(float4*)&tw[0] = ptw[0]; *(float4*)&tw[4] = ptw[1];
        *(float4*)&tb[0] = ptb[0]; *(float4*)&tb[4] = ptb[1];
        *(float4*)&rw2[0] = prw[0]; *(float4*)&rw2[4] = prw[1];
    }

    for (int l = 0; l < L_; ++l) {
        // ---------- all step loads issue up-front ----------
        const float r_re = rand_restart [(size_t)l * NWALK + gid];
        const float r_nb = rand_neighbor[(size_t)l * NWALK + gid];
        const float* __restrict__ mrow    = mem      + (size_t)cur_n * M_;
        const float* __restrict__ nts_row = nbr_time + (size_t)cur_n * D_;
        const int*   __restrict__ ids_row = nbr_ids  + (size_t)cur_n * D_;
        float mv[16];
        {
            const float4* p = reinterpret_cast<const float4*>(mrow) + r * 4;
            float4 v0 = p[0], v1 = p[1], v2 = p[2], v3 = p[3];
            *(float4*)&mv[0] = v0; *(float4*)&mv[4] = v1;
            *(float4*)&mv[8] = v2; *(float4*)&mv[12] = v3;
        }
        float tv[8];
        {
            const float4* p = reinterpret_cast<const float4*>(nts_row) + r * 2;
            float4 v0 = p[0], v1 = p[1];
            *(float4*)&tv[0] = v0; *(float4*)&tv[4] = v1;
        }
        int iv[8];
        {
            const int4* p = reinterpret_cast<const int4*>(ids_row) + r * 2;
            int4 v0 = p[0], v1 = p[1];
            *(int4*)&iv[0] = v0; *(int4*)&iv[4] = v1;
        }
        const int cnt = nbr_cnt[cur_n];

        // ---------- fast time-encoder terms (restart side only) ----------
        // cos(x) = v_cos(fract(x/2pi)); |x|<6 so the reduction is sub-ulp.
        float cosv[8];
        #pragma unroll
        for (int i = 0; i < 8; ++i) {
            const float x = cur_t * tw[i] + tb[i];
            cosv[i] = __builtin_amdgcn_cosf(__builtin_amdgcn_fractf(x * INV2PI));
        }

        float e[8];
        float lmx = -1e9f;
        #pragma unroll
        for (int i = 0; i < 8; ++i) {
            const float tj = tv[i];
            const bool  v  = (tj < cur_t) && ((8 * r + i) < cnt);
            const float s  = v ? (tj - cur_t) / 0.1f : -1e9f;   // true division
            e[i] = s;
            lmx = fmaxf(lmx, s);
        }
        lmx = fmaxf(lmx, dpp_f<XOR1>(lmx));     // xor 1 (exact permute)
        lmx = fmaxf(lmx, dpp_f<XOR2>(lmx));     // xor 2
        lmx = fmaxf(lmx, swz_f<0x101F>(lmx));   // xor 4
        const bool hv = (lmx != -1e9f);

        #pragma unroll
        for (int i = 0; i < 8; ++i) e[i] = expf(e[i] - lmx);   // EXACT (cdf path)

        // ---------- restart logit: full-lane TREE reductions ----------
        float tA = 0.f;
        #pragma unroll
        for (int i = 0; i < 16; ++i) tA += mv[i] * wv[i];   // lane-local fmac chain
        tA += dpp_f<XOR1>(tA);
        tA += dpp_f<XOR2>(tA);
        tA += swz_f<0x101F>(tA);
        float tB = 0.f;
        #pragma unroll
        for (int i = 0; i < 8; ++i) tB += cosv[i] * rw2[i];
        tB += dpp_f<XOR1>(tB);
        tB += dpp_f<XOR2>(tB);
        tB += swz_f<0x101F>(tB);

        const float logits = tA + tB + rb;
        const float p = 1.f / (1.f + expf(-logits));
        const bool restart = r_re < p;

        // ---------- softmax sum: EXACT sequential relay (dpp handoff) ------
        float runS = 0.f;
        #pragma unroll
        for (int rr = 0; rr < 8; ++rr) {
            const float pS = dpp_shr1(runS);
            float tS = pS;
            #pragma unroll
            for (int i = 0; i < 8; ++i) tS += e[i];   // exact j-order adds
            runS = (r == rr) ? tS : runS;
        }
        const float ssum = swz_f<0x00F8>(runS);

        // exact elementwise divisions (identical to baseline)
        float q[8];
        #pragma unroll
        for (int i = 0; i < 8; ++i) q[i] = e[i] / ssum;

        // ---------- CDF relay (adds only, dpp handoff) + parallel count ----
        float pfx[8];
        float runC = 0.f;
        #pragma unroll
        for (int rr = 0; rr < 8; ++rr) {
            const float pC = dpp_shr1(runC);
            if (r == rr) {
                if (rr > 0) runC = pC;
                #pragma unroll
                for (int i = 0; i < 8; ++i) {
                    runC += q[i];          // exact j-order adds
                    pfx[i] = runC;
                }
            }
        }
        int cloc = 0;
        #pragma unroll
        for (int i = 0; i < 8; ++i) cloc += (pfx[i] < r_nb) ? 1 : 0;
        int idx = cloc;   // integer add associative: tree exact
        idx += dpp_i<XOR1>(idx);
        idx += dpp_i<XOR2>(idx);
        idx += swz_i<0x101F>(idx);
        if (idx > D_ - 1) idx = D_ - 1;

        // ---------- in-register selection (no dependent gathers) ----------
        const int owner = idx >> 3;
        const int j     = idx & 7;
        float cand_t = tv[0];
        int   cand_i = iv[0];
        #pragma unroll
        for (int k = 1; k < 8; ++k) {
            cand_t = (j == k) ? tv[k] : cand_t;
            cand_i = (j == k) ? iv[k] : cand_i;
        }
        const float sel_t  = __shfl(cand_t, owner, 8);
        const int   sel_id = __shfl(cand_i, owner, 8);

        const int   step_n = hv ? sel_id : cur_n;
        const float step_t = hv ? sel_t  : cur_t;
        cur_n = restart ? sn : step_n;
        cur_t = restart ? st : step_t;

        if (r == 0) {
            on[l + 1] = (float)cur_n;
            ot[l + 1] = cur_t;
            op[l]     = p;
        }
    }
}

extern "C" void kernel_launch(void* const* d_in, const int* in_sizes, int n_in,
                              void* d_out, int out_size, void* d_ws, size_t ws_size,
                              hipStream_t stream) {
    const int*   nbr_ids       = (const int*)  d_in[0];
    const float* nbr_time      = (const float*)d_in[1];
    const int*   nbr_cnt       = (const int*)  d_in[2];
    const int*   start_nodes   = (const int*)  d_in[3];
    const float* start_times   = (const float*)d_in[4];
    const float* memst         = (const float*)d_in[5];
    const float* time_w        = (const float*)d_in[6];
    const float* time_b        = (const float*)d_in[7];
    const float* restart_w     = (const float*)d_in[8];
    const float* restart_b     = (const float*)d_in[9];
    const float* rand_restart  = (const float*)d_in[10];
    const float* rand_neighbor = (const float*)d_in[11];

    float* out_nodes = (float*)d_out;
    float* out_times = out_nodes + (size_t)B_ * W_ * (L_ + 1);
    float* out_probs = out_times + (size_t)B_ * W_ * (L_ + 1);

    const int threads = 256;
    const int blocks  = (NWALK * K_ + threads - 1) / threads;   // 1280
    hipLaunchKernelGGL(walk_kernel, dim3(blocks), dim3(threads), 0, stream,
                       nbr_ids, nbr_time, nbr_cnt, start_nodes, start_times,
                       memst, time_w, time_b, restart_w, restart_b,
                       rand_restart, rand_neighbor,
                       out_nodes, out_times, out_probs);
}